// Round 1
// baseline (2009.866 us; speedup 1.0000x reference)
//
#include <hip/hip_runtime.h>
#include <math.h>

// Problem constants
#define Bq   256
#define Hd   2048
#define Ed   256
#define Ni   200000
#define Tt   4
#define NBITS 8
#define Kk   100
#define Mm   128          // re-rank margin (top-128 by f32 key superset of f64 top-100)
#define NEGP 1.0e6

// ws layout (bytes)
#define OFF_QV64   0ull         // 256*256*8   = 524288
#define OFF_QCODES 524288ull    // 4*256*4     = 4096
#define OFF_ICODES 528384ull    // 200000*4    = 800000
#define OFF_CAND   1572864ull   // 256*128*4   = 131072
#define OFF_KEYS   2097152ull   // 256*200000*4= 204800000  (total ~197.3 MiB)

// ---------------------------------------------------------------------------
// Kernel A: qv = tanh(layernorm(hidden @ Wq + bq)) in f64; write f32 + f64
// grid 16 blocks x 256 threads; each block does 16 queries, thread = one e.
// ---------------------------------------------------------------------------
__global__ void qproj_kernel(const float* __restrict__ hidden,
                             const float* __restrict__ Wq,
                             const float* __restrict__ bq,
                             const float* __restrict__ gamma,
                             const float* __restrict__ beta,
                             float* __restrict__ qv_out,
                             double* __restrict__ qv64) {
  const int e = threadIdx.x;            // 0..255
  const int qbase = blockIdx.x * 16;
  __shared__ float hs[16][64];
  __shared__ double red[256];
  __shared__ double s_mu[16], s_rs[16];

  double acc[16];
#pragma unroll
  for (int i = 0; i < 16; ++i) acc[i] = 0.0;

  for (int h0 = 0; h0 < Hd; h0 += 64) {
    for (int j = threadIdx.x; j < 16 * 64; j += 256) {
      int qq = j >> 6, hh = j & 63;
      hs[qq][hh] = hidden[(size_t)(qbase + qq) * Hd + h0 + hh];
    }
    __syncthreads();
    for (int hh = 0; hh < 64; ++hh) {
      double w = (double)Wq[(size_t)(h0 + hh) * Ed + e];
#pragma unroll
      for (int qq = 0; qq < 16; ++qq)
        acc[qq] = fma((double)hs[qq][hh], w, acc[qq]);
    }
    __syncthreads();
  }

  const double bv = (double)bq[e];
#pragma unroll
  for (int qq = 0; qq < 16; ++qq) acc[qq] += bv;

  // LayerNorm stats per query (block-wide tree reductions over the 256 e's)
  for (int qq = 0; qq < 16; ++qq) {
    red[threadIdx.x] = acc[qq];
    __syncthreads();
    for (int s = 128; s > 0; s >>= 1) {
      if (threadIdx.x < s) red[threadIdx.x] += red[threadIdx.x + s];
      __syncthreads();
    }
    if (threadIdx.x == 0) s_mu[qq] = red[0] / 256.0;
    __syncthreads();
    double d = acc[qq] - s_mu[qq];
    red[threadIdx.x] = d * d;
    __syncthreads();
    for (int s = 128; s > 0; s >>= 1) {
      if (threadIdx.x < s) red[threadIdx.x] += red[threadIdx.x + s];
      __syncthreads();
    }
    if (threadIdx.x == 0) s_rs[qq] = 1.0 / sqrt(red[0] / 256.0 + 1e-5);
    __syncthreads();
  }

  const double g = (double)gamma[e], bt = (double)beta[e];
  for (int qq = 0; qq < 16; ++qq) {
    double y = (acc[qq] - s_mu[qq]) * s_rs[qq] * g + bt;
    double t = tanh(y);
    int q = qbase + qq;
    qv_out[(size_t)q * Ed + e] = (float)t;
    qv64[(size_t)q * Ed + e] = t;
  }
}

// ---------------------------------------------------------------------------
// Kernel Q: query hash codes. grid 256 blocks x 64 threads.
// thread t<32 computes dot(qv64[q], proj[:,t_table,bit]) in f64; ballot packs.
// ---------------------------------------------------------------------------
__global__ void qcode_kernel(const double* __restrict__ qv64,
                             const float* __restrict__ proj,
                             unsigned int* __restrict__ qcodes) {
  const int q = blockIdx.x;
  const int tid = threadIdx.x;
  double dot = 0.0;
  if (tid < 32) {
    int t = tid >> 3, b = tid & 7;
    const float* pp = proj + (size_t)t * Ed * NBITS + b;
    const double* qr = qv64 + (size_t)q * Ed;
    for (int e = 0; e < Ed; ++e)
      dot = fma(qr[e], (double)pp[(size_t)e * NBITS], dot);
  }
  unsigned long long mask = __ballot(tid < 32 && dot > 0.0);
  if (tid == 0) {
    for (int t = 0; t < Tt; ++t)
      qcodes[t * Bq + q] = (unsigned int)((mask >> (8 * t)) & 0xFFull);
  }
}

// ---------------------------------------------------------------------------
// Kernel I: item hash codes (f64 dots). grid 3125 blocks x 256 threads.
// thread = (item_local = tid>>2, table = tid&3), computes 8 bit-dots.
// proj staged in LDS with per-table bank offset (stride 2056) -> conflict-free.
// ---------------------------------------------------------------------------
__global__ void icode_kernel(const float* __restrict__ item,
                             const float* __restrict__ proj,
                             unsigned int* __restrict__ icodes) {
  __shared__ __align__(16) float pl[Tt][2056];
  const int tid = threadIdx.x;
  for (int j = tid; j < Tt * Ed * NBITS; j += 256) {
    int t = j >> 11, r = j & 2047;
    pl[t][r] = proj[j];
  }
  __syncthreads();

  const int il = tid >> 2, t = tid & 3;
  const int i = blockIdx.x * 64 + il;
  const float* er = item + (size_t)i * Ed;

  double acc[8];
#pragma unroll
  for (int b = 0; b < 8; ++b) acc[b] = 0.0;

  for (int e = 0; e < Ed; ++e) {
    double ev = (double)er[e];
    const float4* p4 = reinterpret_cast<const float4*>(&pl[t][e * 8]);
    float4 x = p4[0], y = p4[1];
    acc[0] = fma(ev, (double)x.x, acc[0]);
    acc[1] = fma(ev, (double)x.y, acc[1]);
    acc[2] = fma(ev, (double)x.z, acc[2]);
    acc[3] = fma(ev, (double)x.w, acc[3]);
    acc[4] = fma(ev, (double)y.x, acc[4]);
    acc[5] = fma(ev, (double)y.y, acc[5]);
    acc[6] = fma(ev, (double)y.z, acc[6]);
    acc[7] = fma(ev, (double)y.w, acc[7]);
  }

  unsigned int byte = 0;
#pragma unroll
  for (int b = 0; b < 8; ++b) byte |= (acc[b] > 0.0 ? 1u : 0u) << b;
  unsigned int v = byte << (8 * t);
  v |= __shfl_xor(v, 1);
  v |= __shfl_xor(v, 2);
  if (t == 0) icodes[i] = v;
}

// ---------------------------------------------------------------------------
// Kernel F: masked score keys (f32). C[q,i] = qv.item; non-candidates -1e6;
// store monotonic-u32 key. Tile 64q x 128i x 32e, 256 threads (16x16),
// per-thread 4q x 8i. grid (4 q-tiles, 1563 i-tiles).
// ---------------------------------------------------------------------------
#define BM 64
#define BN 128
#define BK 32
__global__ void score_kernel(const double* __restrict__ qv64,
                             const float* __restrict__ item,
                             const unsigned int* __restrict__ qcodes,
                             const unsigned int* __restrict__ icodes,
                             unsigned int* __restrict__ keys) {
  __shared__ __align__(16) float As[BK][68];    // [e][q]
  __shared__ __align__(16) float Bs[BK][132];   // [e][i]
  __shared__ unsigned long long bm[Tt][256];    // bucket -> 64-bit query mask

  const int tid = threadIdx.x;
  const int tx = tid & 15, ty = tid >> 4;
  const int qbase = blockIdx.x * BM;
  const int ibase = blockIdx.y * BN;

  // build LSH bucket bitmaps for this block's 64 queries
  {
    unsigned long long* bmf = &bm[0][0];
    for (int j = tid; j < Tt * 256; j += 256) bmf[j] = 0ull;
    __syncthreads();
    int t = tid >> 6, qq = tid & 63;
    unsigned int code = qcodes[t * Bq + qbase + qq];
    atomicOr(&bm[t][code], 1ull << qq);
  }

  float acc[4][8];
#pragma unroll
  for (int a = 0; a < 4; ++a)
#pragma unroll
    for (int b = 0; b < 8; ++b) acc[a][b] = 0.0f;

  for (int e0 = 0; e0 < Ed; e0 += BK) {
    __syncthreads();
    for (int j = tid; j < BM * BK; j += 256) {   // 8 iters
      int q = j >> 5, e = j & 31;
      As[e][q] = (float)qv64[(size_t)(qbase + q) * Ed + e0 + e];
    }
    for (int j = tid; j < BN * BK; j += 256) {   // 16 iters
      int ir = j >> 5, e = j & 31;
      int gi = ibase + ir;
      Bs[e][ir] = (gi < Ni) ? item[(size_t)gi * Ed + e0 + e] : 0.0f;
    }
    __syncthreads();
#pragma unroll 8
    for (int k = 0; k < BK; ++k) {
      float4 av = *reinterpret_cast<const float4*>(&As[k][ty * 4]);
      float4 b0 = *reinterpret_cast<const float4*>(&Bs[k][tx * 8]);
      float4 b1 = *reinterpret_cast<const float4*>(&Bs[k][tx * 8 + 4]);
      float a[4] = {av.x, av.y, av.z, av.w};
      float b[8] = {b0.x, b0.y, b0.z, b0.w, b1.x, b1.y, b1.z, b1.w};
#pragma unroll
      for (int qq = 0; qq < 4; ++qq)
#pragma unroll
        for (int ii = 0; ii < 8; ++ii)
          acc[qq][ii] = fmaf(a[qq], b[ii], acc[qq][ii]);
    }
  }

  // epilogue: mask + monotonic key + store
  unsigned long long m[8];
#pragma unroll
  for (int ii = 0; ii < 8; ++ii) {
    int gi = ibase + tx * 8 + ii;
    unsigned int ci = (gi < Ni) ? icodes[gi] : 0u;
    m[ii] = bm[0][ci & 255u] | bm[1][(ci >> 8) & 255u] |
            bm[2][(ci >> 16) & 255u] | bm[3][(ci >> 24) & 255u];
  }
  const int gi0 = ibase + tx * 8;
#pragma unroll
  for (int qq = 0; qq < 4; ++qq) {
    const int ql = ty * 4 + qq;
    const int q = qbase + ql;
    unsigned int kv[8];
#pragma unroll
    for (int ii = 0; ii < 8; ++ii) {
      float s = acc[qq][ii];
      if (!((m[ii] >> ql) & 1ull)) s -= (float)NEGP;
      unsigned int u = __float_as_uint(s);
      u = (u & 0x80000000u) ? ~u : (u | 0x80000000u);
      kv[ii] = u;
    }
    if (gi0 + 7 < Ni) {
      uint4* dst = reinterpret_cast<uint4*>(&keys[(size_t)q * Ni + gi0]);
      dst[0] = make_uint4(kv[0], kv[1], kv[2], kv[3]);
      dst[1] = make_uint4(kv[4], kv[5], kv[6], kv[7]);
    } else {
      for (int ii = 0; ii < 8; ++ii)
        if (gi0 + ii < Ni) keys[(size_t)q * Ni + gi0 + ii] = kv[ii];
    }
  }
}

// ---------------------------------------------------------------------------
// Kernel D: per-query top-128 select by f32 key. 256 blocks x 256 threads.
// Pass1: 8192-bin histogram of key>>19 (run-length cached atomics).
// Pass2: collect all items in bins >= beta, bitonic sort desc, emit 128 ids.
// ---------------------------------------------------------------------------
#define NBINS 8192
#define CAP   8192
__global__ void select_kernel(const unsigned int* __restrict__ keys,
                              unsigned int* __restrict__ cand) {
  __shared__ unsigned long long list[CAP];         // 64 KiB (aliased w/ hist)
  __shared__ unsigned int partial[256];
  __shared__ int scnt, sbeta;
  unsigned int* hist = reinterpret_cast<unsigned int*>(list);  // 8192 u32

  const int q = blockIdx.x, tid = threadIdx.x;
  const unsigned int* row = keys + (size_t)q * Ni;

  for (int j = tid; j < NBINS; j += 256) hist[j] = 0u;
  __syncthreads();

  {
    int lastBin = -1;
    unsigned int cnt = 0;
    for (int i = tid; i < Ni; i += 256) {
      int bin = (int)(row[i] >> 19);
      if (bin == lastBin) {
        ++cnt;
      } else {
        if (lastBin >= 0) atomicAdd(&hist[lastBin], cnt);
        lastBin = bin;
        cnt = 1;
      }
    }
    if (lastBin >= 0) atomicAdd(&hist[lastBin], cnt);
  }
  __syncthreads();

  unsigned int s = 0;
  for (int j = 0; j < 32; ++j) s += hist[tid * 32 + j];
  partial[tid] = s;
  __syncthreads();

  if (tid == 0) {
    unsigned int cum = 0;
    int c;
    for (c = 255; c > 0; --c) {
      if (cum + partial[c] >= (unsigned)Mm) break;
      cum += partial[c];
    }
    int b;
    for (b = c * 32 + 31; b > c * 32; --b) {
      if (cum + hist[b] >= (unsigned)Mm) break;
      cum += hist[b];
    }
    sbeta = b;
    scnt = 0;
  }
  __syncthreads();
  const int beta = sbeta;
  __syncthreads();   // hist no longer needed; list reuse begins

  for (int i = tid; i < Ni; i += 256) {
    unsigned int u = row[i];
    if ((int)(u >> 19) >= beta) {
      int pos = atomicAdd(&scnt, 1);
      if (pos < CAP)
        list[pos] = ((unsigned long long)u << 32) | (unsigned int)(~(unsigned int)i);
    }
  }
  __syncthreads();

  int count = scnt < CAP ? scnt : CAP;
  int n = Mm;
  while (n < count) n <<= 1;
  for (int j = tid; j < n; j += 256)
    if (j >= count) list[j] = 0ull;
  __syncthreads();

  // bitonic sort, descending (key desc => value desc, index asc on ties)
  for (int k2 = 2; k2 <= n; k2 <<= 1) {
    for (int j = k2 >> 1; j > 0; j >>= 1) {
      for (int i = tid; i < n; i += 256) {
        int l = i ^ j;
        if (l > i) {
          bool up = ((i & k2) == 0);
          unsigned long long a = list[i], b = list[l];
          if ((a < b) == up) { list[i] = b; list[l] = a; }
        }
      }
      __syncthreads();
    }
  }

  if (tid < Mm) {
    unsigned long long v = list[tid];
    cand[q * Mm + tid] = ~(unsigned int)(v & 0xFFFFFFFFull);
  }
}

// ---------------------------------------------------------------------------
// Kernel E: f64 re-rank of 128 candidates/query; sort (score desc, id asc);
// emit 100 ids (as float) + gathered embeddings. 256 blocks x 256 threads.
// ---------------------------------------------------------------------------
__global__ void rerank_kernel(const double* __restrict__ qv64,
                              const float* __restrict__ item,
                              const unsigned int* __restrict__ qcodes,
                              const unsigned int* __restrict__ icodes,
                              const unsigned int* __restrict__ cand,
                              float* __restrict__ out_ids,
                              float* __restrict__ out_emb) {
  const int q = blockIdx.x, tid = threadIdx.x;
  __shared__ double qr[Ed];
  __shared__ double sc[Mm];
  __shared__ int sid[Mm];

  qr[tid] = qv64[(size_t)q * Ed + tid];
  __syncthreads();

  if (tid < Mm) {
    int id = (int)cand[q * Mm + tid];
    const float* er = item + (size_t)id * Ed;
    double acc = 0.0;
    for (int e = 0; e < Ed; ++e) acc = fma(qr[e], (double)er[e], acc);
    unsigned int ci = icodes[id];
    bool match = false;
#pragma unroll
    for (int t = 0; t < Tt; ++t)
      match = match || (((ci >> (8 * t)) & 255u) == qcodes[t * Bq + q]);
    if (!match) acc -= NEGP;
    sc[tid] = acc;
    sid[tid] = id;
  }
  __syncthreads();

  for (int k2 = 2; k2 <= Mm; k2 <<= 1) {
    for (int j = k2 >> 1; j > 0; j >>= 1) {
      for (int i = tid; i < Mm; i += 256) {
        int l = i ^ j;
        if (l > i) {
          bool up = ((i & k2) == 0);
          double sa = sc[i], sb = sc[l];
          int ia = sid[i], ib = sid[l];
          bool aAfterB = (sa < sb) || (sa == sb && ia > ib);
          if (aAfterB == up) {
            sc[i] = sb; sc[l] = sa;
            sid[i] = ib; sid[l] = ia;
          }
        }
      }
      __syncthreads();
    }
  }

  if (tid < Kk) out_ids[q * Kk + tid] = (float)sid[tid];
  for (int j = tid; j < Kk * Ed; j += 256) {
    int r = j >> 8, e = j & 255;
    out_emb[((size_t)q * Kk + r) * Ed + e] = item[(size_t)sid[r] * Ed + e];
  }
}

// ---------------------------------------------------------------------------
extern "C" void kernel_launch(void* const* d_in, const int* in_sizes, int n_in,
                              void* d_out, int out_size, void* d_ws, size_t ws_size,
                              hipStream_t stream) {
  const float* hidden = (const float*)d_in[0];
  const float* Wq     = (const float*)d_in[1];
  const float* bq     = (const float*)d_in[2];
  const float* gamma  = (const float*)d_in[3];
  const float* beta   = (const float*)d_in[4];
  const float* proj   = (const float*)d_in[5];
  const float* item   = (const float*)d_in[6];

  float* out = (float*)d_out;
  char* ws = (char*)d_ws;
  double*       qv64   = (double*)(ws + OFF_QV64);
  unsigned int* qcodes = (unsigned int*)(ws + OFF_QCODES);
  unsigned int* icodes = (unsigned int*)(ws + OFF_ICODES);
  unsigned int* cand   = (unsigned int*)(ws + OFF_CAND);
  unsigned int* keys   = (unsigned int*)(ws + OFF_KEYS);

  qproj_kernel<<<dim3(16), dim3(256), 0, stream>>>(hidden, Wq, bq, gamma, beta,
                                                   out, qv64);
  qcode_kernel<<<dim3(Bq), dim3(64), 0, stream>>>(qv64, proj, qcodes);
  icode_kernel<<<dim3(Ni / 64), dim3(256), 0, stream>>>(item, proj, icodes);
  score_kernel<<<dim3(Bq / BM, (Ni + BN - 1) / BN), dim3(256), 0, stream>>>(
      qv64, item, qcodes, icodes, keys);
  select_kernel<<<dim3(Bq), dim3(256), 0, stream>>>(keys, cand);
  rerank_kernel<<<dim3(Bq), dim3(256), 0, stream>>>(
      qv64, item, qcodes, icodes, cand,
      out + (size_t)Bq * Ed, out + (size_t)Bq * Ed + (size_t)Bq * Kk);
}

// Round 2
// 1220.196 us; speedup vs baseline: 1.6472x; 1.6472x over previous
//
#include <hip/hip_runtime.h>
#include <math.h>

// Problem constants
#define Bq   256
#define Hd   2048
#define Ed   256
#define Ni   200000
#define Tt   4
#define NBITS 8
#define Kk   100
#define Mm   128            // rerank margin: top-128 by approx key superset of true top-100
#define CAPL 16384          // per-query compact candidate list capacity
#define CAP2 4096           // select LDS collect capacity
#define NBINS 8192

typedef short short8 __attribute__((ext_vector_type(8)));
typedef float f32x4 __attribute__((ext_vector_type(4)));

// ws layout (bytes)
#define OFF_QV64  0ull            // 256*256*8   = 524288
#define OFF_QVBF  524288ull       // 256*256*2   = 131072
#define OFF_QC    655360ull       // 256*4       = 1024
#define OFF_IC    656384ull       // 200000*4    = 800000
#define OFF_CNT   1456384ull      // 256*4
#define OFF_CAND  1458432ull      // 256*128*4   = 131072
#define OFF_IBF   1589504ull      // 200000*256*2 = 102400000
#define OFF_LIST  103989504ull    // 256*16384*8  = 33554432  (total ~137.5 MB)

__device__ __forceinline__ unsigned short f2bf(float x) {
  unsigned u = __float_as_uint(x);
  return (unsigned short)((u + 0x7FFFu + ((u >> 16) & 1u)) >> 16);
}
__device__ __forceinline__ bool anybyte_eq(unsigned a, unsigned b) {
  unsigned x = a ^ b;
  return ((x - 0x01010101u) & ~x & 0x80808080u) != 0u;
}
__device__ __forceinline__ unsigned fkey(float s) {
  unsigned u = __float_as_uint(s);
  return (u & 0x80000000u) ? ~u : (u | 0x80000000u);
}

typedef __attribute__((address_space(1))) const unsigned int GU32;
typedef __attribute__((address_space(3))) unsigned int LU32;
__device__ __forceinline__ void gload16(const void* g, void* l) {
  __builtin_amdgcn_global_load_lds((GU32*)g, (LU32*)l, 16, 0, 0);
}

// histogram beta-find helper (shared across select/fallback)
__device__ __forceinline__ int find_beta(unsigned* hist, unsigned* partial_,
                                         int* sbeta, int tid, int target) {
  unsigned s = 0;
#pragma unroll 8
  for (int j = 0; j < 32; ++j) s += hist[tid * 32 + j];
  partial_[tid] = s;
  __syncthreads();
  if (tid == 0) {
    unsigned cum = 0;
    int c;
    for (c = 255; c > 0; --c) {
      if (cum + partial_[c] >= (unsigned)target) break;
      cum += partial_[c];
    }
    int b;
    for (b = c * 32 + 31; b > c * 32; --b) {
      if (cum + hist[b] >= (unsigned)target) break;
      cum += hist[b];
    }
    *sbeta = b;
  }
  __syncthreads();
  return *sbeta;
}

// ---------------------------------------------------------------------------
// Kernel A: per-query projection (f64) + LayerNorm + tanh + fused query hash.
// grid 256 blocks x 256 threads; block = one query, thread = one e.
// Also zeroes the per-query candidate counters.
// ---------------------------------------------------------------------------
__global__ void qproj_kernel(const float* __restrict__ hidden,
                             const float* __restrict__ Wq,
                             const float* __restrict__ bq,
                             const float* __restrict__ gamma,
                             const float* __restrict__ beta,
                             const float* __restrict__ proj,
                             float* __restrict__ out_qv,
                             double* __restrict__ qv64,
                             unsigned short* __restrict__ qvbf,
                             unsigned* __restrict__ qcp,
                             unsigned* __restrict__ cnt) {
  const int q = blockIdx.x, e = threadIdx.x;
  __shared__ float hs[Hd];
  __shared__ double red[256];
  __shared__ double qd[256];
  __shared__ double s_mu, s_rs;

  if (e == 0) cnt[q] = 0u;

#pragma unroll
  for (int r = 0; r < 2; ++r) {
    int fi = e + 256 * r;
    *reinterpret_cast<float4*>(&hs[fi * 4]) =
        *reinterpret_cast<const float4*>(&hidden[(size_t)q * Hd + fi * 4]);
  }
  __syncthreads();

  double acc = 0.0;
#pragma unroll 16
  for (int h = 0; h < Hd; ++h)
    acc = fma((double)hs[h], (double)Wq[(size_t)h * Ed + e], acc);
  acc += (double)bq[e];

  red[e] = acc;
  __syncthreads();
  for (int s = 128; s > 0; s >>= 1) {
    if (e < s) red[e] += red[e + s];
    __syncthreads();
  }
  if (e == 0) s_mu = red[0] / 256.0;
  __syncthreads();
  double d = acc - s_mu;
  red[e] = d * d;
  __syncthreads();
  for (int s = 128; s > 0; s >>= 1) {
    if (e < s) red[e] += red[e + s];
    __syncthreads();
  }
  if (e == 0) s_rs = 1.0 / sqrt(red[0] / 256.0 + 1e-5);
  __syncthreads();

  double y = (acc - s_mu) * s_rs * (double)gamma[e] + (double)beta[e];
  double t = tanh(y);
  out_qv[(size_t)q * Ed + e] = (float)t;
  qv64[(size_t)q * Ed + e] = t;
  qvbf[(size_t)q * Ed + e] = f2bf((float)t);
  qd[e] = t;
  __syncthreads();

  // fused query hash codes (f64 sign decisions)
  double dot = 0.0;
  if (e < 32) {
    const int tt = e >> 3, b = e & 7;
    const float* pp = proj + (size_t)tt * Ed * NBITS + b;
#pragma unroll 4
    for (int ee = 0; ee < Ed; ++ee)
      dot = fma(qd[ee], (double)pp[(size_t)ee * NBITS], dot);
  }
  unsigned long long mask = __ballot(e < 32 && dot > 0.0);
  if (e == 0) qcp[q] = (unsigned)mask;
}

// ---------------------------------------------------------------------------
// Kernel I: item hash codes (f64, LDS-staged) + fused f32->bf16 conversion.
// grid 3125 blocks x 256 threads; block = 64 items, K-chunked by 64.
// ---------------------------------------------------------------------------
__global__ void icode_kernel(const float* __restrict__ item,
                             const float* __restrict__ proj,
                             unsigned* __restrict__ icodes,
                             unsigned short* __restrict__ ibf) {
  __shared__ float pl[Tt][2056];     // proj, per-table bank stagger
  __shared__ float ts[64][68];       // item tile chunk, padded stride
  const int tid = threadIdx.x;
  const int base = blockIdx.x * 64;

  for (int j = tid; j < Tt * Ed * NBITS; j += 256) {
    int t = j >> 11, r = j & 2047;
    pl[t][r] = proj[j];
  }

  const int il = tid >> 2, t = tid & 3;
  double acc[8];
#pragma unroll
  for (int b = 0; b < 8; ++b) acc[b] = 0.0;

  for (int e0 = 0; e0 < Ed; e0 += 64) {
    __syncthreads();
    // stage 64x64 f32 chunk coalesced + emit bf16
#pragma unroll
    for (int r = 0; r < 4; ++r) {
      int fi = tid + 256 * r;
      int row = fi >> 4, c4 = fi & 15;
      float4 v = *reinterpret_cast<const float4*>(
          &item[(size_t)(base + row) * Ed + e0 + c4 * 4]);
      *reinterpret_cast<float4*>(&ts[row][c4 * 4]) = v;
      ushort4 hv;
      hv.x = f2bf(v.x); hv.y = f2bf(v.y); hv.z = f2bf(v.z); hv.w = f2bf(v.w);
      *reinterpret_cast<ushort4*>(&ibf[(size_t)(base + row) * Ed + e0 + c4 * 4]) = hv;
    }
    __syncthreads();
#pragma unroll 4
    for (int e = 0; e < 64; ++e) {
      double ev = (double)ts[il][e];
      const float4* p4 = reinterpret_cast<const float4*>(&pl[t][(e0 + e) * 8]);
      float4 x = p4[0], y = p4[1];
      acc[0] = fma(ev, (double)x.x, acc[0]);
      acc[1] = fma(ev, (double)x.y, acc[1]);
      acc[2] = fma(ev, (double)x.z, acc[2]);
      acc[3] = fma(ev, (double)x.w, acc[3]);
      acc[4] = fma(ev, (double)y.x, acc[4]);
      acc[5] = fma(ev, (double)y.y, acc[5]);
      acc[6] = fma(ev, (double)y.z, acc[6]);
      acc[7] = fma(ev, (double)y.w, acc[7]);
    }
  }

  unsigned byte = 0;
#pragma unroll
  for (int b = 0; b < 8; ++b) byte |= (acc[b] > 0.0 ? 1u : 0u) << b;
  unsigned v = byte << (8 * t);
  v |= __shfl_xor(v, 1);
  v |= __shfl_xor(v, 2);
  if (t == 0) icodes[base + il] = v;
}

// ---------------------------------------------------------------------------
// Kernel F: bf16 MFMA score GEMM (m97 structure) + compact candidate push.
// BM=256 (all queries) x BN=64 items, BK=32, 4 waves x acc[4][4] of 16x16x32.
// grid 3125 blocks x 256 threads. Epilogue pushes matched (key,~id) pairs.
// ---------------------------------------------------------------------------
__global__ void __launch_bounds__(256) score_kernel(
    const unsigned short* __restrict__ qvbf,
    const unsigned short* __restrict__ ibf,
    const unsigned* __restrict__ qcp,
    const unsigned* __restrict__ icodes,
    unsigned* __restrict__ cnt,
    unsigned long long* __restrict__ list) {
  __shared__ unsigned short As[256 * 32];   // 16 KB  [qrow][k]
  __shared__ unsigned short Bs[64 * 32];    // 4 KB   [irow][k]
  __shared__ unsigned qc_s[256];
  __shared__ unsigned ic_s[64];

  const int tid = threadIdx.x;
  const int ibase = blockIdx.x * 64;
  const int l = tid & 63, w = tid >> 6;
  const int li = l & 15, lh = l >> 4;

  qc_s[tid] = qcp[tid];
  if (tid < 64) ic_s[tid] = icodes[ibase + tid];

  f32x4 acc[4][4] = {};

  for (int k0 = 0; k0 < Ed; k0 += 32) {
    __syncthreads();
    // stage A: 1024 x 16B chunks (4/lane); B: 256 chunks (1/lane)
#pragma unroll
    for (int rep = 0; rep < 4; ++rep) {
      int ch = rep * 256 + tid;
      int row = ch >> 2, c8 = (ch & 3) * 8;
      gload16(qvbf + (size_t)row * Ed + k0 + c8, (char*)As + ch * 16);
    }
    {
      int ch = tid;
      int row = ch >> 2, c8 = (ch & 3) * 8;
      gload16(ibf + (size_t)(ibase + row) * Ed + k0 + c8, (char*)Bs + ch * 16);
    }
    __syncthreads();

    short8 af[4], bfv[4];
#pragma unroll
    for (int m = 0; m < 4; ++m)
      af[m] = *reinterpret_cast<const short8*>(&As[(w * 64 + m * 16 + li) * 32 + lh * 8]);
#pragma unroll
    for (int n = 0; n < 4; ++n)
      bfv[n] = *reinterpret_cast<const short8*>(&Bs[(n * 16 + li) * 32 + lh * 8]);
#pragma unroll
    for (int m = 0; m < 4; ++m)
#pragma unroll
      for (int n = 0; n < 4; ++n)
        acc[m][n] = __builtin_amdgcn_mfma_f32_16x16x32_bf16(af[m], bfv[n], acc[m][n], 0, 0, 0);
  }

  // epilogue: candidacy test + compact push
  unsigned ic_l[4];
  int i_l[4];
#pragma unroll
  for (int n = 0; n < 4; ++n) {
    i_l[n] = ibase + n * 16 + li;
    ic_l[n] = ic_s[n * 16 + li];
  }
#pragma unroll
  for (int m = 0; m < 4; ++m)
#pragma unroll
    for (int r = 0; r < 4; ++r) {
      const int q = w * 64 + m * 16 + lh * 4 + r;
      const unsigned qc = qc_s[q];
#pragma unroll
      for (int n = 0; n < 4; ++n) {
        if (anybyte_eq(qc, ic_l[n])) {
          unsigned pos = atomicAdd(&cnt[q], 1u);
          if (pos < CAPL)
            list[(size_t)q * CAPL + pos] =
                ((unsigned long long)fkey(acc[m][n][r]) << 32) |
                (unsigned)(~(unsigned)i_l[n]);
        }
      }
    }
}

// ---------------------------------------------------------------------------
// Kernel FB: brute-force fallback for queries with cnt<Mm or list overflow.
// Never expected to run (cnt ~3100); correctness-only path.
// ---------------------------------------------------------------------------
__global__ void fallback_kernel(const double* __restrict__ qv64,
                                const float* __restrict__ item,
                                const unsigned* __restrict__ qcp,
                                const unsigned* __restrict__ icodes,
                                unsigned* __restrict__ cnt,
                                unsigned long long* __restrict__ list) {
  const int q = blockIdx.x, tid = threadIdx.x;
  unsigned c = cnt[q];
  if (c >= (unsigned)Mm && c <= (unsigned)CAPL) return;

  __shared__ unsigned hist[NBINS];
  __shared__ float qf[256];
  __shared__ unsigned partial_[256];
  __shared__ int sbeta, scnt;

  qf[tid] = (float)qv64[(size_t)q * Ed + tid];
  for (int j = tid; j < NBINS; j += 256) hist[j] = 0u;
  if (tid == 0) scnt = 0;
  __syncthreads();

  const unsigned qc = qcp[q];
  for (int i = tid; i < Ni; i += 256) {
    float s = 0.0f;
    const float* er = item + (size_t)i * Ed;
    for (int e = 0; e < Ed; ++e) s = fmaf(qf[e], er[e], s);
    if (!anybyte_eq(qc, icodes[i])) s -= 1.0e6f;
    atomicAdd(&hist[fkey(s) >> 19], 1u);
  }
  __syncthreads();

  int beta = find_beta(hist, partial_, &sbeta, tid, Mm);
  __syncthreads();

  for (int i = tid; i < Ni; i += 256) {
    float s = 0.0f;
    const float* er = item + (size_t)i * Ed;
    for (int e = 0; e < Ed; ++e) s = fmaf(qf[e], er[e], s);
    if (!anybyte_eq(qc, icodes[i])) s -= 1.0e6f;
    unsigned k = fkey(s);
    if ((int)(k >> 19) >= beta) {
      int pos = atomicAdd(&scnt, 1);
      if (pos < CAPL)
        list[(size_t)q * CAPL + pos] =
            ((unsigned long long)k << 32) | (unsigned)(~(unsigned)i);
    }
  }
  __syncthreads();
  if (tid == 0) cnt[q] = (unsigned)(scnt < CAPL ? scnt : CAPL);
}

// ---------------------------------------------------------------------------
// Kernel D: top-128 select from compact list (hist threshold + bitonic).
// grid 256 blocks x 256 threads.
// ---------------------------------------------------------------------------
__global__ void select_kernel(const unsigned long long* __restrict__ list,
                              const unsigned* __restrict__ cnt,
                              unsigned* __restrict__ cand) {
  __shared__ unsigned long long buf[CAP2];   // 32 KB (aliased with hist)
  __shared__ unsigned partial_[256];
  __shared__ int sbeta, scnt;
  unsigned* hist = reinterpret_cast<unsigned*>(buf);

  const int q = blockIdx.x, tid = threadIdx.x;
  const unsigned long long* src = list + (size_t)q * CAPL;
  const int count = min((int)cnt[q], CAPL);

  for (int j = tid; j < NBINS; j += 256) hist[j] = 0u;
  if (tid == 0) scnt = 0;
  __syncthreads();

  for (int i = tid; i < count; i += 256)
    atomicAdd(&hist[(unsigned)(src[i] >> 32) >> 19], 1u);
  __syncthreads();

  int beta = find_beta(hist, partial_, &sbeta, tid, Mm);
  __syncthreads();   // hist dead; buf reuse begins

  for (int i = tid; i < count; i += 256) {
    unsigned long long v = src[i];
    if ((int)((unsigned)(v >> 32) >> 19) >= beta) {
      int pos = atomicAdd(&scnt, 1);
      if (pos < CAP2) buf[pos] = v;
    }
  }
  __syncthreads();

  int sc = min(scnt, CAP2);
  int n = Mm;
  while (n < sc) n <<= 1;
  for (int j = tid; j < n; j += 256)
    if (j >= sc) buf[j] = 0ull;
  __syncthreads();

  for (int k2 = 2; k2 <= n; k2 <<= 1) {
    for (int j = k2 >> 1; j > 0; j >>= 1) {
      for (int i = tid; i < n; i += 256) {
        int p = i ^ j;
        if (p > i) {
          bool up = ((i & k2) == 0);
          unsigned long long a = buf[i], b = buf[p];
          if ((a < b) == up) { buf[i] = b; buf[p] = a; }
        }
      }
      __syncthreads();
    }
  }

  if (tid < Mm)
    cand[q * Mm + tid] = ~(unsigned)(buf[tid] & 0xFFFFFFFFull);
}

// ---------------------------------------------------------------------------
// Kernel E: f64 re-rank of 128 candidates (wave-cooperative dots);
// sort (score desc, id asc); emit 100 ids (as f32) + gathered embeddings.
// ---------------------------------------------------------------------------
__global__ void rerank_kernel(const double* __restrict__ qv64,
                              const float* __restrict__ item,
                              const unsigned* __restrict__ qcp,
                              const unsigned* __restrict__ icodes,
                              const unsigned* __restrict__ cand,
                              float* __restrict__ out_ids,
                              float* __restrict__ out_emb) {
  const int q = blockIdx.x, tid = threadIdx.x;
  const int l = tid & 63, w = tid >> 6;
  __shared__ double qr[Ed];
  __shared__ double sc[Mm];
  __shared__ int sid[Mm];

  qr[tid] = qv64[(size_t)q * Ed + tid];
  if (tid < Mm) {
    int id = (int)cand[q * Mm + tid];
    if (id < 0 || id >= Ni) id = 0;
    sid[tid] = id;
  }
  __syncthreads();

  const unsigned qc = qcp[q];
  for (int cc = 0; cc < Mm / 4; ++cc) {
    const int ci = w * (Mm / 4) + cc;
    const int id = sid[ci];
    float4 ev = *reinterpret_cast<const float4*>(&item[(size_t)id * Ed + l * 4]);
    double p = fma((double)ev.x, qr[l * 4 + 0],
               fma((double)ev.y, qr[l * 4 + 1],
               fma((double)ev.z, qr[l * 4 + 2],
                   (double)ev.w * qr[l * 4 + 3])));
#pragma unroll
    for (int off = 32; off > 0; off >>= 1) p += __shfl_down(p, off);
    if (l == 0) {
      double s = p;
      if (!anybyte_eq(qc, icodes[id])) s -= 1.0e6;
      sc[ci] = s;
    }
  }
  __syncthreads();

  for (int k2 = 2; k2 <= Mm; k2 <<= 1) {
    for (int j = k2 >> 1; j > 0; j >>= 1) {
      for (int i = tid; i < Mm; i += 256) {
        int p = i ^ j;
        if (p > i) {
          bool up = ((i & k2) == 0);
          double sa = sc[i], sb = sc[p];
          int ia = sid[i], ib = sid[p];
          bool aAfterB = (sa < sb) || (sa == sb && ia > ib);
          if (aAfterB == up) {
            sc[i] = sb; sc[p] = sa;
            sid[i] = ib; sid[p] = ia;
          }
        }
      }
      __syncthreads();
    }
  }

  if (tid < Kk) out_ids[q * Kk + tid] = (float)sid[tid];
  // gather embeddings: 100 rows x 64 float4, coalesced
  for (int f = tid; f < Kk * 64; f += 256) {
    int r = f >> 6, c4 = f & 63;
    *reinterpret_cast<float4*>(&out_emb[((size_t)q * Kk + r) * Ed + c4 * 4]) =
        *reinterpret_cast<const float4*>(&item[(size_t)sid[r] * Ed + c4 * 4]);
  }
}

// ---------------------------------------------------------------------------
extern "C" void kernel_launch(void* const* d_in, const int* in_sizes, int n_in,
                              void* d_out, int out_size, void* d_ws, size_t ws_size,
                              hipStream_t stream) {
  const float* hidden = (const float*)d_in[0];
  const float* Wq     = (const float*)d_in[1];
  const float* bq     = (const float*)d_in[2];
  const float* gamma  = (const float*)d_in[3];
  const float* beta   = (const float*)d_in[4];
  const float* proj   = (const float*)d_in[5];
  const float* item   = (const float*)d_in[6];

  float* out = (float*)d_out;
  char* ws = (char*)d_ws;
  double*             qv64 = (double*)(ws + OFF_QV64);
  unsigned short*     qvbf = (unsigned short*)(ws + OFF_QVBF);
  unsigned*           qcp  = (unsigned*)(ws + OFF_QC);
  unsigned*           ic   = (unsigned*)(ws + OFF_IC);
  unsigned*           cnt  = (unsigned*)(ws + OFF_CNT);
  unsigned*           cand = (unsigned*)(ws + OFF_CAND);
  unsigned short*     ibf  = (unsigned short*)(ws + OFF_IBF);
  unsigned long long* list = (unsigned long long*)(ws + OFF_LIST);

  qproj_kernel<<<dim3(Bq), dim3(256), 0, stream>>>(hidden, Wq, bq, gamma, beta,
                                                   proj, out, qv64, qvbf, qcp, cnt);
  icode_kernel<<<dim3(Ni / 64), dim3(256), 0, stream>>>(item, proj, ic, ibf);
  score_kernel<<<dim3(Ni / 64), dim3(256), 0, stream>>>(qvbf, ibf, qcp, ic, cnt, list);
  fallback_kernel<<<dim3(Bq), dim3(256), 0, stream>>>(qv64, item, qcp, ic, cnt, list);
  select_kernel<<<dim3(Bq), dim3(256), 0, stream>>>(list, cnt, cand);
  rerank_kernel<<<dim3(Bq), dim3(256), 0, stream>>>(
      qv64, item, qcp, ic, cand,
      out + (size_t)Bq * Ed, out + (size_t)Bq * Ed + (size_t)Bq * Kk);
}

// Round 3
// 621.153 us; speedup vs baseline: 3.2357x; 1.9644x over previous
//
#include <hip/hip_runtime.h>
#include <math.h>

// Problem constants
#define Bq   256
#define Hd   2048
#define Ed   256
#define Ni   200000
#define Tt   4
#define NBITS 8
#define Kk   100
#define Mm   128            // rerank margin: top-128 by approx key superset of true top-100
#define CAPL 16384          // per-query compact candidate list capacity
#define CAPB 3072           // per-block LDS match buffer (slice expects ~390)
#define CAP2 4096           // select LDS collect capacity
#define NBINS 8192
#define NSLICE 8
#define ISLICE (Ni / NSLICE)   // 25000

// ws layout (bytes) — total ~137.4 MB (< R2's proven 137.55 MB)
#define OFF_QV64  0ull            // 256*256*8   = 524288
#define OFF_QC    524288ull       // 256*4       = 1024
#define OFF_IC    525312ull       // 200000*4    = 800000
#define OFF_CNT   1325312ull      // 256*4       = 1024
#define OFF_CAND  1326336ull      // 256*128*4   = 131072
#define OFF_IBF   1457408ull      // 200000*256*2 = 102400000
#define OFF_LIST  103857408ull    // 256*16384*8  = 33554432

__device__ __forceinline__ unsigned short f2bf(float x) {
  unsigned u = __float_as_uint(x);
  return (unsigned short)((u + 0x7FFFu + ((u >> 16) & 1u)) >> 16);
}
__device__ __forceinline__ float bf2f(unsigned short h) {
  return __uint_as_float((unsigned)h << 16);
}
__device__ __forceinline__ bool anybyte_eq(unsigned a, unsigned b) {
  unsigned x = a ^ b;
  return ((x - 0x01010101u) & ~x & 0x80808080u) != 0u;
}
__device__ __forceinline__ unsigned fkey(float s) {
  unsigned u = __float_as_uint(s);
  return (u & 0x80000000u) ? ~u : (u | 0x80000000u);
}

// histogram beta-find helper (shared across select/fallback)
__device__ __forceinline__ int find_beta(unsigned* hist, unsigned* partial_,
                                         int* sbeta, int tid, int target) {
  unsigned s = 0;
#pragma unroll 8
  for (int j = 0; j < 32; ++j) s += hist[tid * 32 + j];
  partial_[tid] = s;
  __syncthreads();
  if (tid == 0) {
    unsigned cum = 0;
    int c;
    for (c = 255; c > 0; --c) {
      if (cum + partial_[c] >= (unsigned)target) break;
      cum += partial_[c];
    }
    int b;
    for (b = c * 32 + 31; b > c * 32; --b) {
      if (cum + hist[b] >= (unsigned)target) break;
      cum += hist[b];
    }
    *sbeta = b;
  }
  __syncthreads();
  return *sbeta;
}

// ---------------------------------------------------------------------------
// Kernel A: per-query projection (f64) + LayerNorm + tanh + fused query hash.
// grid 256 blocks x 256 threads; block = one query, thread = one e.
// Also zeroes the per-query candidate counters.
// ---------------------------------------------------------------------------
__global__ void qproj_kernel(const float* __restrict__ hidden,
                             const float* __restrict__ Wq,
                             const float* __restrict__ bq,
                             const float* __restrict__ gamma,
                             const float* __restrict__ beta,
                             const float* __restrict__ proj,
                             float* __restrict__ out_qv,
                             double* __restrict__ qv64,
                             unsigned* __restrict__ qcp,
                             unsigned* __restrict__ cnt) {
  const int q = blockIdx.x, e = threadIdx.x;
  __shared__ float hs[Hd];
  __shared__ double red[256];
  __shared__ double qd[256];
  __shared__ double s_mu, s_rs;

  if (e == 0) cnt[q] = 0u;

#pragma unroll
  for (int r = 0; r < 2; ++r) {
    int fi = e + 256 * r;
    *reinterpret_cast<float4*>(&hs[fi * 4]) =
        *reinterpret_cast<const float4*>(&hidden[(size_t)q * Hd + fi * 4]);
  }
  __syncthreads();

  double acc = 0.0;
#pragma unroll 16
  for (int h = 0; h < Hd; ++h)
    acc = fma((double)hs[h], (double)Wq[(size_t)h * Ed + e], acc);
  acc += (double)bq[e];

  red[e] = acc;
  __syncthreads();
  for (int s = 128; s > 0; s >>= 1) {
    if (e < s) red[e] += red[e + s];
    __syncthreads();
  }
  if (e == 0) s_mu = red[0] / 256.0;
  __syncthreads();
  double d = acc - s_mu;
  red[e] = d * d;
  __syncthreads();
  for (int s = 128; s > 0; s >>= 1) {
    if (e < s) red[e] += red[e + s];
    __syncthreads();
  }
  if (e == 0) s_rs = 1.0 / sqrt(red[0] / 256.0 + 1e-5);
  __syncthreads();

  double y = (acc - s_mu) * s_rs * (double)gamma[e] + (double)beta[e];
  double t = tanh(y);
  out_qv[(size_t)q * Ed + e] = (float)t;
  qv64[(size_t)q * Ed + e] = t;
  qd[e] = t;
  __syncthreads();

  // fused query hash codes (f64 sign decisions)
  double dot = 0.0;
  if (e < 32) {
    const int tt = e >> 3, b = e & 7;
    const float* pp = proj + (size_t)tt * Ed * NBITS + b;
#pragma unroll 4
    for (int ee = 0; ee < Ed; ++ee)
      dot = fma(qd[ee], (double)pp[(size_t)ee * NBITS], dot);
  }
  unsigned long long mask = __ballot(e < 32 && dot > 0.0);
  if (e == 0) qcp[q] = (unsigned)mask;
}

// ---------------------------------------------------------------------------
// Kernel I: item hash codes (f32 accumulate, f64 recompute for borderline
// |dot| < 2e-3 -> sign decisions equivalent to full f64) + fused bf16 emit.
// grid 3125 blocks x 256 threads; thread = (item_local, table).
// ---------------------------------------------------------------------------
__global__ void icode_kernel(const float* __restrict__ item,
                             const float* __restrict__ proj,
                             unsigned* __restrict__ icodes,
                             unsigned short* __restrict__ ibf) {
  __shared__ float pl[Tt][2056];     // proj, per-table bank stagger
  __shared__ float ts[64][68];       // item tile chunk, padded stride
  const int tid = threadIdx.x;
  const int base = blockIdx.x * 64;

  for (int j = tid; j < Tt * Ed * NBITS; j += 256) {
    int t = j >> 11, r = j & 2047;
    pl[t][r] = proj[j];
  }

  const int il = tid >> 2, t = tid & 3;
  float acc[8];
#pragma unroll
  for (int b = 0; b < 8; ++b) acc[b] = 0.0f;

  for (int e0 = 0; e0 < Ed; e0 += 64) {
    __syncthreads();
    // stage 64x64 f32 chunk coalesced + emit bf16
#pragma unroll
    for (int r = 0; r < 4; ++r) {
      int fi = tid + 256 * r;
      int row = fi >> 4, c4 = fi & 15;
      float4 v = *reinterpret_cast<const float4*>(
          &item[(size_t)(base + row) * Ed + e0 + c4 * 4]);
      *reinterpret_cast<float4*>(&ts[row][c4 * 4]) = v;
      ushort4 hv;
      hv.x = f2bf(v.x); hv.y = f2bf(v.y); hv.z = f2bf(v.z); hv.w = f2bf(v.w);
      *reinterpret_cast<ushort4*>(&ibf[(size_t)(base + row) * Ed + e0 + c4 * 4]) = hv;
    }
    __syncthreads();
#pragma unroll 4
    for (int e = 0; e < 64; ++e) {
      float ev = ts[il][e];
      const float4* p4 = reinterpret_cast<const float4*>(&pl[t][(e0 + e) * 8]);
      float4 x = p4[0], y = p4[1];
      acc[0] = fmaf(ev, x.x, acc[0]);
      acc[1] = fmaf(ev, x.y, acc[1]);
      acc[2] = fmaf(ev, x.z, acc[2]);
      acc[3] = fmaf(ev, x.w, acc[3]);
      acc[4] = fmaf(ev, y.x, acc[4]);
      acc[5] = fmaf(ev, y.y, acc[5]);
      acc[6] = fmaf(ev, y.z, acc[6]);
      acc[7] = fmaf(ev, y.w, acc[7]);
    }
  }

  bool borderline = false;
#pragma unroll
  for (int b = 0; b < 8; ++b) borderline |= (fabsf(acc[b]) < 2e-3f);

  unsigned byte = 0;
  if (borderline) {
    // exact f64 recompute of all 8 bits for this (item, table)
    double a64[8];
#pragma unroll
    for (int b = 0; b < 8; ++b) a64[b] = 0.0;
    const float* er = item + (size_t)(base + il) * Ed;
    for (int e = 0; e < Ed; ++e) {
      double ev = (double)er[e];
#pragma unroll
      for (int b = 0; b < 8; ++b)
        a64[b] = fma(ev, (double)pl[t][e * 8 + b], a64[b]);
    }
#pragma unroll
    for (int b = 0; b < 8; ++b) byte |= (a64[b] > 0.0 ? 1u : 0u) << b;
  } else {
#pragma unroll
    for (int b = 0; b < 8; ++b) byte |= (acc[b] > 0.0f ? 1u : 0u) << b;
  }

  unsigned v = byte << (8 * t);
  v |= __shfl_xor(v, 1);
  v |= __shfl_xor(v, 2);
  if (t == 0) icodes[base + il] = v;
}

// ---------------------------------------------------------------------------
// Kernel F: fused match + candidate scoring. grid (256 q, 8 slices) x 256.
// Each wave scans 64 icodes, ballots matches (~1.5%), then scores each match
// wave-cooperatively (bf16 row gather + f32 dot + butterfly reduce).
// Matches buffered in LDS; ONE global atomicAdd per block reserves a range.
// ---------------------------------------------------------------------------
__global__ void __launch_bounds__(256) score_kernel(
    const float* __restrict__ qvf,
    const unsigned short* __restrict__ ibf,
    const unsigned* __restrict__ icodes,
    const unsigned* __restrict__ qcp,
    unsigned* __restrict__ cnt,
    unsigned long long* __restrict__ list) {
  __shared__ unsigned long long buf[CAPB];   // 24 KB
  __shared__ int lcnt;
  __shared__ unsigned sbase;

  const int tid = threadIdx.x;
  const int q = blockIdx.x;
  const int sl = blockIdx.y;
  const int l = tid & 63, wid = tid >> 6;

  if (tid == 0) lcnt = 0;
  const unsigned qc = qcp[q];
  const float4 qv4 = *reinterpret_cast<const float4*>(&qvf[(size_t)q * Ed + l * 4]);
  __syncthreads();

  const int i0 = sl * ISLICE, i1 = i0 + ISLICE;
  for (int bse = i0 + wid * 64; bse < i1; bse += 256) {
    const int i = bse + l;
    bool m = (i < i1) && anybyte_eq(qc, icodes[i]);
    unsigned long long mask = __ballot(m);
    while (mask) {
      const int b = __builtin_ctzll(mask);
      mask &= mask - 1;
      const int ii = bse + b;
      // wave-cooperative bf16 dot: 8B/lane, 512B coalesced
      ushort4 hv = *reinterpret_cast<const ushort4*>(&ibf[(size_t)ii * Ed + l * 4]);
      float p = fmaf(bf2f(hv.x), qv4.x,
                fmaf(bf2f(hv.y), qv4.y,
                fmaf(bf2f(hv.z), qv4.z, bf2f(hv.w) * qv4.w)));
#pragma unroll
      for (int off = 1; off < 64; off <<= 1) p += __shfl_xor(p, off);
      if (l == 0) {
        int pos = atomicAdd(&lcnt, 1);
        if (pos < CAPB)
          buf[pos] = ((unsigned long long)fkey(p) << 32) |
                     (unsigned)(~(unsigned)ii);
      }
    }
  }
  __syncthreads();

  const int nl = lcnt;
  if (nl > CAPB) {           // overflow: force brute-force fallback for q
    if (tid == 0) atomicAdd(&cnt[q], (unsigned)(CAPL + 1));
    return;
  }
  if (tid == 0) sbase = atomicAdd(&cnt[q], (unsigned)nl);
  __syncthreads();
  const unsigned bp = sbase;
  for (int j = tid; j < nl; j += 256) {
    unsigned p = bp + (unsigned)j;
    if (p < CAPL) list[(size_t)q * CAPL + p] = buf[j];
  }
}

// ---------------------------------------------------------------------------
// Kernel FB: brute-force fallback for queries with cnt<Mm or overflow.
// Never expected to run with random data; correctness-only path.
// ---------------------------------------------------------------------------
__global__ void fallback_kernel(const double* __restrict__ qv64,
                                const float* __restrict__ item,
                                const unsigned* __restrict__ qcp,
                                const unsigned* __restrict__ icodes,
                                unsigned* __restrict__ cnt,
                                unsigned long long* __restrict__ list) {
  const int q = blockIdx.x, tid = threadIdx.x;
  unsigned c = cnt[q];
  if (c >= (unsigned)Mm && c <= (unsigned)CAPL) return;

  __shared__ unsigned hist[NBINS];
  __shared__ float qf[256];
  __shared__ unsigned partial_[256];
  __shared__ int sbeta, scnt;

  qf[tid] = (float)qv64[(size_t)q * Ed + tid];
  for (int j = tid; j < NBINS; j += 256) hist[j] = 0u;
  if (tid == 0) scnt = 0;
  __syncthreads();

  const unsigned qc = qcp[q];
  for (int i = tid; i < Ni; i += 256) {
    float s = 0.0f;
    const float* er = item + (size_t)i * Ed;
    for (int e = 0; e < Ed; ++e) s = fmaf(qf[e], er[e], s);
    if (!anybyte_eq(qc, icodes[i])) s -= 1.0e6f;
    atomicAdd(&hist[fkey(s) >> 19], 1u);
  }
  __syncthreads();

  int beta = find_beta(hist, partial_, &sbeta, tid, Mm);
  __syncthreads();

  for (int i = tid; i < Ni; i += 256) {
    float s = 0.0f;
    const float* er = item + (size_t)i * Ed;
    for (int e = 0; e < Ed; ++e) s = fmaf(qf[e], er[e], s);
    if (!anybyte_eq(qc, icodes[i])) s -= 1.0e6f;
    unsigned k = fkey(s);
    if ((int)(k >> 19) >= beta) {
      int pos = atomicAdd(&scnt, 1);
      if (pos < CAPL)
        list[(size_t)q * CAPL + pos] =
            ((unsigned long long)k << 32) | (unsigned)(~(unsigned)i);
    }
  }
  __syncthreads();
  if (tid == 0) cnt[q] = (unsigned)(scnt < CAPL ? scnt : CAPL);
}

// ---------------------------------------------------------------------------
// Kernel D: top-128 select from compact list (hist threshold + bitonic).
// grid 256 blocks x 256 threads.
// ---------------------------------------------------------------------------
__global__ void select_kernel(const unsigned long long* __restrict__ list,
                              const unsigned* __restrict__ cnt,
                              unsigned* __restrict__ cand) {
  __shared__ unsigned long long buf[CAP2];   // 32 KB (aliased with hist)
  __shared__ unsigned partial_[256];
  __shared__ int sbeta, scnt;
  unsigned* hist = reinterpret_cast<unsigned*>(buf);

  const int q = blockIdx.x, tid = threadIdx.x;
  const unsigned long long* src = list + (size_t)q * CAPL;
  const int count = min((int)cnt[q], CAPL);

  for (int j = tid; j < NBINS; j += 256) hist[j] = 0u;
  if (tid == 0) scnt = 0;
  __syncthreads();

  for (int i = tid; i < count; i += 256)
    atomicAdd(&hist[(unsigned)(src[i] >> 32) >> 19], 1u);
  __syncthreads();

  int beta = find_beta(hist, partial_, &sbeta, tid, Mm);
  __syncthreads();   // hist dead; buf reuse begins

  for (int i = tid; i < count; i += 256) {
    unsigned long long v = src[i];
    if ((int)((unsigned)(v >> 32) >> 19) >= beta) {
      int pos = atomicAdd(&scnt, 1);
      if (pos < CAP2) buf[pos] = v;
    }
  }
  __syncthreads();

  int sc = min(scnt, CAP2);
  int n = Mm;
  while (n < sc) n <<= 1;
  for (int j = tid; j < n; j += 256)
    if (j >= sc) buf[j] = 0ull;
  __syncthreads();

  for (int k2 = 2; k2 <= n; k2 <<= 1) {
    for (int j = k2 >> 1; j > 0; j >>= 1) {
      for (int i = tid; i < n; i += 256) {
        int p = i ^ j;
        if (p > i) {
          bool up = ((i & k2) == 0);
          unsigned long long a = buf[i], b = buf[p];
          if ((a < b) == up) { buf[i] = b; buf[p] = a; }
        }
      }
      __syncthreads();
    }
  }

  if (tid < Mm)
    cand[q * Mm + tid] = ~(unsigned)(buf[tid] & 0xFFFFFFFFull);
}

// ---------------------------------------------------------------------------
// Kernel E: f64 re-rank of 128 candidates (wave-cooperative dots);
// sort (score desc, id asc); emit 100 ids (as f32) + gathered embeddings.
// ---------------------------------------------------------------------------
__global__ void rerank_kernel(const double* __restrict__ qv64,
                              const float* __restrict__ item,
                              const unsigned* __restrict__ qcp,
                              const unsigned* __restrict__ icodes,
                              const unsigned* __restrict__ cand,
                              float* __restrict__ out_ids,
                              float* __restrict__ out_emb) {
  const int q = blockIdx.x, tid = threadIdx.x;
  const int l = tid & 63, w = tid >> 6;
  __shared__ double qr[Ed];
  __shared__ double sc[Mm];
  __shared__ int sid[Mm];

  qr[tid] = qv64[(size_t)q * Ed + tid];
  if (tid < Mm) {
    int id = (int)cand[q * Mm + tid];
    if (id < 0 || id >= Ni) id = 0;
    sid[tid] = id;
  }
  __syncthreads();

  const unsigned qc = qcp[q];
  for (int cc = 0; cc < Mm / 4; ++cc) {
    const int ci = w * (Mm / 4) + cc;
    const int id = sid[ci];
    float4 ev = *reinterpret_cast<const float4*>(&item[(size_t)id * Ed + l * 4]);
    double p = fma((double)ev.x, qr[l * 4 + 0],
               fma((double)ev.y, qr[l * 4 + 1],
               fma((double)ev.z, qr[l * 4 + 2],
                   (double)ev.w * qr[l * 4 + 3])));
#pragma unroll
    for (int off = 32; off > 0; off >>= 1) p += __shfl_down(p, off);
    if (l == 0) {
      double s = p;
      if (!anybyte_eq(qc, icodes[id])) s -= 1.0e6;
      sc[ci] = s;
    }
  }
  __syncthreads();

  for (int k2 = 2; k2 <= Mm; k2 <<= 1) {
    for (int j = k2 >> 1; j > 0; j >>= 1) {
      for (int i = tid; i < Mm; i += 256) {
        int p = i ^ j;
        if (p > i) {
          bool up = ((i & k2) == 0);
          double sa = sc[i], sb = sc[p];
          int ia = sid[i], ib = sid[p];
          bool aAfterB = (sa < sb) || (sa == sb && ia > ib);
          if (aAfterB == up) {
            sc[i] = sb; sc[p] = sa;
            sid[i] = ib; sid[p] = ia;
          }
        }
      }
      __syncthreads();
    }
  }

  if (tid < Kk) out_ids[q * Kk + tid] = (float)sid[tid];
  // gather embeddings: 100 rows x 64 float4, coalesced
  for (int f = tid; f < Kk * 64; f += 256) {
    int r = f >> 6, c4 = f & 63;
    *reinterpret_cast<float4*>(&out_emb[((size_t)q * Kk + r) * Ed + c4 * 4]) =
        *reinterpret_cast<const float4*>(&item[(size_t)sid[r] * Ed + c4 * 4]);
  }
}

// ---------------------------------------------------------------------------
extern "C" void kernel_launch(void* const* d_in, const int* in_sizes, int n_in,
                              void* d_out, int out_size, void* d_ws, size_t ws_size,
                              hipStream_t stream) {
  const float* hidden = (const float*)d_in[0];
  const float* Wq     = (const float*)d_in[1];
  const float* bq     = (const float*)d_in[2];
  const float* gamma  = (const float*)d_in[3];
  const float* beta   = (const float*)d_in[4];
  const float* proj   = (const float*)d_in[5];
  const float* item   = (const float*)d_in[6];

  float* out = (float*)d_out;
  char* ws = (char*)d_ws;
  double*             qv64 = (double*)(ws + OFF_QV64);
  unsigned*           qcp  = (unsigned*)(ws + OFF_QC);
  unsigned*           ic   = (unsigned*)(ws + OFF_IC);
  unsigned*           cnt  = (unsigned*)(ws + OFF_CNT);
  unsigned*           cand = (unsigned*)(ws + OFF_CAND);
  unsigned short*     ibf  = (unsigned short*)(ws + OFF_IBF);
  unsigned long long* list = (unsigned long long*)(ws + OFF_LIST);

  qproj_kernel<<<dim3(Bq), dim3(256), 0, stream>>>(hidden, Wq, bq, gamma, beta,
                                                   proj, out, qv64, qcp, cnt);
  icode_kernel<<<dim3(Ni / 64), dim3(256), 0, stream>>>(item, proj, ic, ibf);
  score_kernel<<<dim3(Bq, NSLICE), dim3(256), 0, stream>>>(out, ibf, ic, qcp, cnt, list);
  fallback_kernel<<<dim3(Bq), dim3(256), 0, stream>>>(qv64, item, qcp, ic, cnt, list);
  select_kernel<<<dim3(Bq), dim3(256), 0, stream>>>(list, cnt, cand);
  rerank_kernel<<<dim3(Bq), dim3(256), 0, stream>>>(
      qv64, item, qcp, ic, cand,
      out + (size_t)Bq * Ed, out + (size_t)Bq * Ed + (size_t)Bq * Kk);
}